// Round 1
// baseline (74.588 us; speedup 1.0000x reference)
//
#include <hip/hip_runtime.h>

#define NROW 4096      // 64*64 patch positions
#define BATCH 8
#define XPLANE (65*65) // per-batch-image plane

// ws layout: float s[4096]; float acc; unsigned cnt;

__global__ void __launch_bounds__(256) k_scalar(const float* __restrict__ x,
                                                float* __restrict__ s,
                                                float* acc, unsigned* cnt) {
    int n = blockIdx.x * 256 + threadIdx.x;
    if (n == 0) { *acc = 0.0f; *cnt = 0u; }
    int i = n >> 6, j = n & 63;
    const float* p = x + i * 65 + j;
    float sum = 0.0f;
#pragma unroll
    for (int b = 0; b < BATCH; ++b) {
        const float* q = p + b * XPLANE;
        sum += (q[0] + q[1]) + (q[65] + q[66]);
    }
    s[n] = tanhf(sum * (1.0f / 32.0f));
}

__global__ void __launch_bounds__(256) k_attn(const float* __restrict__ s,
                                              float* acc, unsigned* cnt,
                                              const float* __restrict__ proj_w,
                                              const float* __restrict__ proj_b,
                                              float* __restrict__ out,
                                              int nblocks) {
    __shared__ float s_sh[NROW];
    __shared__ float c_sh[16];
    const int tid = threadIdx.x;

    // stage s into LDS (coalesced, conflict-free)
    for (int k = tid; k < NROW; k += 256) s_sh[k] = s[k];
    __syncthreads();

    // 16 rows per block, 16 threads per row; interleaved m (lane L hits bank
    // (L+16k)%32 with 4-lane broadcast -> conflict-free)
    const int row = blockIdx.x * 16 + (tid >> 4);
    const int m0  = tid & 15;
    const float sn = s_sh[row];
    const float t  = 8.0f * 1.4426950408889634f * sn; // fold log2(e) into scale
    float num = 0.0f, den = 0.0f;
#pragma unroll 8
    for (int k = 0; k < 256; ++k) {
        float sm = s_sh[m0 + (k << 4)];
        float e  = exp2f(t * sm);      // |t*sm| < 11.6 -> safe, no max-subtract
        num += e * sm;
        den += e;
    }
#pragma unroll
    for (int off = 8; off; off >>= 1) {
        num += __shfl_down(num, off, 16);
        den += __shfl_down(den, off, 16);
    }
    if (m0 == 0) c_sh[tid >> 4] = num / den;
    __syncthreads();

    if (tid == 0) {
        float bs = 0.0f;
#pragma unroll
        for (int r = 0; r < 16; ++r) bs += c_sh[r];
        atomicAdd(acc, bs);
        __threadfence();
        unsigned old = atomicAdd(cnt, 1u);
        if (old == (unsigned)(nblocks - 1)) {
            // last block: all other blocks' acc adds are visible
            __threadfence();
            float total = atomicAdd(acc, 0.0f);   // coherent read of final sum
            float P = total * (1.0f / (float)NROW);
            float W = 0.0f;
            for (int d = 0; d < 64; ++d) W += proj_w[d];
            float o = P * W + proj_b[0];
#pragma unroll
            for (int b = 0; b < BATCH; ++b) out[b] = o;
        }
    }
}

extern "C" void kernel_launch(void* const* d_in, const int* in_sizes, int n_in,
                              void* d_out, int out_size, void* d_ws, size_t ws_size,
                              hipStream_t stream) {
    const float* x      = (const float*)d_in[0];
    const float* proj_w = (const float*)d_in[1];
    const float* proj_b = (const float*)d_in[2];
    float* out = (float*)d_out;

    float*    s   = (float*)d_ws;
    float*    acc = s + NROW;
    unsigned* cnt = (unsigned*)(acc + 1);

    // kernel 1 zeroes acc/cnt (thread n==0); stream order makes it visible
    k_scalar<<<16, 256, 0, stream>>>(x, s, acc, cnt);
    k_attn<<<256, 256, 0, stream>>>(s, acc, cnt, proj_w, proj_b, out, 256);
}

// Round 2
// 71.634 us; speedup vs baseline: 1.0412x; 1.0412x over previous
//
#include <hip/hip_runtime.h>

#define NROW 4096      // 64*64 patch positions
#define NCOL 4225      // 65*65 plane
#define BATCH 8
#define MAGIC 0x13579BDFu

// ws layout: float partial[256]; unsigned flags[256];

__global__ void __launch_bounds__(256) k_fused(const float* __restrict__ x,
                                               const float* __restrict__ proj_w,
                                               const float* __restrict__ proj_b,
                                               float* __restrict__ out,
                                               float* __restrict__ partial,
                                               unsigned* __restrict__ flags) {
    __shared__ float cs_sh[NCOL];   // batch-summed plane
    __shared__ float s_sh[NROW];    // tanh scalars
    __shared__ float c_sh[16];      // per-row softmax results
    const int tid = threadIdx.x;
    const int bid = blockIdx.x;

    // phase 1: colsum[p] = sum_b x[b,p]  (coalesced: consecutive tid -> consecutive p)
    for (int p = tid; p < NCOL; p += 256) {
        float v = 0.0f;
#pragma unroll
        for (int b = 0; b < BATCH; ++b) v += x[b * NCOL + p];
        cs_sh[p] = v;
    }
    __syncthreads();

    // phase 2: s[n] = tanh(2x2 patch sum / 32)
#pragma unroll
    for (int k = 0; k < 16; ++k) {
        int n = tid + (k << 8);
        int i = n >> 6, j = n & 63;
        const float* c = &cs_sh[i * 65 + j];
        s_sh[n] = tanhf((c[0] + c[1] + c[65] + c[66]) * (1.0f / 32.0f));
    }
    __syncthreads();

    // phase 3: 16 rows/block, 16 lanes/row; stride-16 m-index -> conflict-free
    const int row = (bid << 4) + (tid >> 4);
    const int m0  = tid & 15;
    const float t = 8.0f * 1.4426950408889634f * s_sh[row];  // fold log2(e)
    float num = 0.0f, den = 0.0f;
#pragma unroll 8
    for (int k = 0; k < 256; ++k) {
        float sm = s_sh[m0 + (k << 4)];
        float e  = exp2f(t * sm);   // |arg| < 11.6, no max-subtraction needed
        num += e * sm;
        den += e;
    }
#pragma unroll
    for (int off = 8; off; off >>= 1) {
        num += __shfl_down(num, off, 16);
        den += __shfl_down(den, off, 16);
    }
    if (m0 == 0) c_sh[tid >> 4] = num / den;
    __syncthreads();

    // phase 4: publish block partial (atomic RMW -> device-coherent; no init needed)
    if (tid == 0) {
        float bs = 0.0f;
#pragma unroll
        for (int r = 0; r < 16; ++r) bs += c_sh[r];
        atomicExch(&partial[bid], bs);
        __threadfence();
        atomicExch(&flags[bid], MAGIC);
    }

    // phase 5: block 0, wave 0 waits for all partials and finalizes.
    // All other blocks retire unconditionally -> no deadlock under any scheduling.
    if (bid == 0 && tid < 64) {
#pragma unroll
        for (int q = 0; q < 4; ++q) {
            int i = tid + (q << 6);
            while (atomicAdd(&flags[i], 0u) != MAGIC) {}
        }
        __threadfence();
        float acc_c = 0.0f;
#pragma unroll
        for (int q = 0; q < 4; ++q) {
            int i = tid + (q << 6);
            acc_c += atomicAdd(&partial[i], 0.0f);  // coherent read
        }
        float pw = proj_w[tid];  // 64 lanes, one weight each
#pragma unroll
        for (int off = 32; off; off >>= 1) {
            acc_c += __shfl_down(acc_c, off, 64);
            pw    += __shfl_down(pw, off, 64);
        }
        if (tid == 0) {
            float o = (acc_c * (1.0f / (float)NROW)) * pw + proj_b[0];
#pragma unroll
            for (int b = 0; b < BATCH; ++b) out[b] = o;
        }
    }
}

extern "C" void kernel_launch(void* const* d_in, const int* in_sizes, int n_in,
                              void* d_out, int out_size, void* d_ws, size_t ws_size,
                              hipStream_t stream) {
    const float* x      = (const float*)d_in[0];
    const float* proj_w = (const float*)d_in[1];
    const float* proj_b = (const float*)d_in[2];
    float* out = (float*)d_out;

    float*    partial = (float*)d_ws;
    unsigned* flags   = (unsigned*)(partial + 256);

    k_fused<<<256, 256, 0, stream>>>(x, proj_w, proj_b, out, partial, flags);
}